// Round 14
// baseline (132.066 us; speedup 1.0000x reference)
//
#include <hip/hip_runtime.h>
#include <math.h>

#define NA 500000
#define NE 1000000
#define NB 100000
#define HID 128
#define NCHUNK 489      // ceil(NA / 1024)
#define NT 7813         // ceil(NA / 64) worst-case ctx tiles
#define NBT 1563        // ceil(NB / 64)
#define NAC 272000      // capacity for compacted ctx atoms (~250K actual)
#define CAPA 14         // per-atom kept-degree cap; Poisson(1), P(>=14 anywhere) ~ 1e-6
#define NEB 977         // edge-quad blocks in k_escfat
#define NAB 1954        // atom blocks in k_escfat
#define NZB 364         // zero-fill blocks in k_scanprep (93000 int4 / 256)

typedef __attribute__((ext_vector_type(8))) short bf16x8;
typedef __attribute__((ext_vector_type(4))) float f32x4;

// fp32 -> bf16 round-to-nearest-even
static __device__ __forceinline__ unsigned short bf1(float a) {
    unsigned ua = __float_as_uint(a);
    ua += 0x7fffu + ((ua >> 16) & 1u);
    return (unsigned short)(ua >> 16);
}
static __device__ __forceinline__ unsigned bfpack(float a, float b) {
    unsigned ua = __float_as_uint(a); ua += 0x7fffu + ((ua >> 16) & 1u);
    unsigned ub = __float_as_uint(b); ub += 0x7fffu + ((ub >> 16) & 1u);
    return (ua >> 16) | (ub & 0xffff0000u);
}
static __device__ __forceinline__ float bff(unsigned short h) {
    return __uint_as_float((unsigned)h << 16);
}

// ---- K1 (fat): blocks [0,489): ctx scan (acp packs A);
//                [489,553): TAW/MTW prep; [553,617): wt2;
//                [617,981): zero cnt+adeg (1.488 MB) ----
__global__ __launch_bounds__(256) void k_scanprep(
    const int* __restrict__ block_ids, const int* __restrict__ gmask,
    const int* __restrict__ A,
    int* __restrict__ zbase, int* __restrict__ acp, int* __restrict__ totB,
    const float* __restrict__ at, const float* __restrict__ bt,
    const float* __restrict__ W1, const float* __restrict__ W2,
    const float* __restrict__ b1, const float* __restrict__ epsp,
    float* __restrict__ TAW, float* __restrict__ MTW,
    unsigned short* __restrict__ wt2)
{
    __shared__ float smem[17920];   // 70 KB, shared by all branches
    const int blk = blockIdx.x;
    const int tid = threadIdx.x;

    if (blk < NCHUNK) {
        // per-chunk exclusive ctx scan; acp[i] = (prefix<<7)|A[i] or -1
        int* sd = (int*)smem;
        int base = blk * 1024 + tid * 4;
        int c0 = 0, c1 = 0, c2 = 0, c3 = 0;
        int4 av = make_int4(0, 0, 0, 0);
        if (base < NA) {               // NA%4==0 -> all 4 valid
            int4 b = *(const int4*)(block_ids + base);
            av = *(const int4*)(A + base);
            c0 = (gmask[b.x] == 0); c1 = (gmask[b.y] == 0);
            c2 = (gmask[b.z] == 0); c3 = (gmask[b.w] == 0);
        }
        int s = c0 + c1 + c2 + c3;
        sd[tid] = s;
        __syncthreads();
        for (int o = 1; o < 256; o <<= 1) {
            int x = (tid >= o) ? sd[tid - o] : 0;
            __syncthreads();
            sd[tid] += x;
            __syncthreads();
        }
        int run = sd[tid] - s;
        if (tid == 255) totB[blk] = sd[255];
        if (base < NA) {
            acp[base + 0] = c0 ? ((run << 7) | av.x) : -1; run += c0;
            acp[base + 1] = c1 ? ((run << 7) | av.y) : -1; run += c1;
            acp[base + 2] = c2 ? ((run << 7) | av.z) : -1; run += c2;
            acp[base + 3] = c3 ? ((run << 7) | av.w) : -1;
        }
    } else if (blk < NCHUNK + 64) {
        // TAW' = (1+eps)*(at@W1)+b1 (rows 0..127); MTW = relu(at+bt)@W1 (rows 128..767)
        const int blk2 = blk - NCHUNK;
        float* sW1 = smem;                              // 64 KB
        float (*sIn)[HID] = (float(*)[HID])(smem + 16384);  // 6 KB
        for (int i = tid; i < HID * HID / 4; i += 256)
            ((float4*)sW1)[i] = ((const float4*)W1)[i];
        for (int x = tid; x < 12 * HID; x += 256) {
            int rr = x >> 7, k = x & 127;
            int r = blk2 * 12 + rr;                     // 0..767
            float v = 0.f;
            if (r < 128) v = at[r * HID + k];
            else {
                int m = r - 128;
                int a = m / 5, bb = m - a * 5;
                v = fmaxf(at[a * HID + k] + bt[bb * HID + k], 0.f);
            }
            sIn[rr][k] = v;
        }
        __syncthreads();
        float ope = 1.0f + epsp[0];
        for (int x = tid; x < 12 * HID; x += 256) {
            int rr = x >> 7, c = x & 127;
            int r = blk2 * 12 + rr;
            float acc = 0.f;
#pragma unroll 8
            for (int k = 0; k < HID; ++k)
                acc = fmaf(sIn[rr][k], sW1[k * HID + c], acc);
            if (r < 128) TAW[r * HID + c] = ope * acc + b1[c];
            else         MTW[(r - 128) * HID + c] = acc;
        }
    } else if (blk < NCHUNK + 128) {
        // wt2 = bf16 col-major W2 [n][k]
        int id = (blk - NCHUNK - 64) * 256 + tid;       // 0..16383
        int n = id >> 7, k = id & 127;
        wt2[id] = bf1(W2[k * HID + n]);
    } else {
        // zero cnt+adeg region: 1488000 B = 93000 int4
        int id = (blk - NCHUNK - 128) * 256 + tid;
        if (id < 93000) ((int4*)zbase)[id] = make_int4(0, 0, 0, 0);
    }
}

// ---- K2 (fat): every block scans totB (2KB) in-LDS; then
//      blocks [0,NEB): edge scatter with global pd;
//      blocks [NEB,NEB+NAB): cnt histogram + catomA + boundary-row zeroing ----
__global__ __launch_bounds__(256) void k_escfat(
    const int* __restrict__ bonds, const int* __restrict__ acp,
    const int* __restrict__ totB, const int* __restrict__ block_ids,
    int* __restrict__ adeg, unsigned short* __restrict__ buf2,
    int* __restrict__ catomA, int* __restrict__ nctxp,
    int* __restrict__ cnt, float* __restrict__ out)
{
    __shared__ int sT[512];
    __shared__ int sS[256];
    const int t = threadIdx.x;
    // exclusive scan of chunk totals (pairs per thread)
    int a0 = (2 * t     < NCHUNK) ? totB[2 * t]     : 0;
    int a1 = (2 * t + 1 < NCHUNK) ? totB[2 * t + 1] : 0;
    int s = a0 + a1;
    sS[t] = s;
    __syncthreads();
    for (int o = 1; o < 256; o <<= 1) {
        int x = (t >= o) ? sS[t - o] : 0;
        __syncthreads();
        sS[t] += x;
        __syncthreads();
    }
    int run = sS[t] - s;
    sT[2 * t] = run;
    sT[2 * t + 1] = run + a0;
    if (blockIdx.x == 0 && t == 255) nctxp[0] = sS[255];
    __syncthreads();

    if (blockIdx.x < NEB) {
        int e4 = blockIdx.x * 256 + t;           // edge-quad id
        if (e4 >= NE / 4) return;
        const int4* b4 = (const int4*)bonds;
        int4 q0 = b4[e4 * 3 + 0];
        int4 q1 = b4[e4 * 3 + 1];
        int4 q2 = b4[e4 * 3 + 2];
        int ss[4] = {q0.x, q0.w, q1.z, q2.y};
        int dd[4] = {q0.y, q1.x, q1.w, q2.z};
        int tt[4] = {q0.z, q1.y, q2.x, q2.w};
#pragma unroll
        for (int k = 0; k < 4; ++k) {
            int va = acp[ss[k]];
            int vd = acp[dd[k]];
            if ((va | vd) >= 0) {                // both ctx
                int pd = (vd >> 7) + sT[dd[k] >> 10];
                int slot = atomicAdd(&adeg[pd], 1);
                if (slot < CAPA)
                    buf2[(size_t)pd * CAPA + slot] =
                        (unsigned short)((va & 127) * 5 + tt[k]);   // < 640
            }
        }
    } else {
        int i = (blockIdx.x - NEB) * 256 + t;
        if (i < NA) {
            int bid = block_ids[i];
            atomicAdd(&cnt[bid], 1);             // per-block atom count
            int v = acp[i];
            if (v >= 0) {
                int p = (v >> 7) + sT[i >> 10];
                catomA[p] = (bid << 7) | (v & 127);   // bid<2^17
                int pm = p & 15;
                if (pm == 0 || pm == 15) {
                    // quarter-segment boundary: zero its out row (atomic target)
                    float4 z = make_float4(0.f, 0.f, 0.f, 0.f);
                    float4* o = (float4*)(out + (size_t)bid * HID);
#pragma unroll
                    for (int j = 0; j < 32; ++j) o[j] = z;
                }
            }
        }
    }
}

// ---- K3: 512-thread tiles; 8 threads/atom walk; swizzled bf16 sH;
//          register-prefetched segmented block-sum (4 quarters x 16 rows) ----
__global__ __launch_bounds__(512, 8) void k_h1(
    const int* __restrict__ catomA, const int* __restrict__ nctxp,
    const int* __restrict__ adeg, const unsigned short* __restrict__ buf2,
    const float* __restrict__ TAW, const float* __restrict__ MTW,
    float* __restrict__ out)
{
    __shared__ unsigned short sH[64 * 128];   // 16 KB, chunk-XOR swizzled
    __shared__ int sAid[64];
    __shared__ int sBid[64];
    __shared__ int sDeg[64];

    const int nctx = nctxp[0];
    const int base = blockIdx.x * 64;
    if (base >= nctx) return;          // uniform exit
    const int tid = threadIdx.x;

    if (tid < 64) {
        int idx = base + tid;
        if (idx < nctx) {
            int ca = catomA[idx];
            sAid[tid] = ca & 127;
            sBid[tid] = ca >> 7;
            int d = adeg[idx];
            sDeg[tid] = d < CAPA ? d : CAPA;
        } else {
            sAid[tid] = -1; sBid[tid] = -1; sDeg[tid] = 0;
        }
    }
    __syncthreads();

    // compute: thread (al, ks8) owns 16 cols of atom al
    {
        const int al = tid >> 3;            // atom-local 0..63
        const int ks8 = (tid & 7) * 16;     // col-segment base
        const int aid = sAid[al];
        float hacc[16];
#pragma unroll
        for (int j = 0; j < 16; ++j) hacc[j] = 0.f;
        if (aid >= 0) {
            const int deg = sDeg[al];
            const unsigned* ep32 = (const unsigned*)(buf2 + (size_t)(base + al) * CAPA);
            unsigned ev[7];
#pragma unroll
            for (int j = 0; j < 7; ++j)
                if (2 * j < deg) ev[j] = ep32[j];
            const float4* tp = (const float4*)(TAW + aid * HID + ks8);
#pragma unroll
            for (int j = 0; j < 4; ++j) {
                float4 v = tp[j];
                hacc[4 * j + 0] = v.x; hacc[4 * j + 1] = v.y;
                hacc[4 * j + 2] = v.z; hacc[4 * j + 3] = v.w;
            }
#pragma unroll
            for (int j = 0; j < 7; ++j) {
                if (2 * j < deg) {
                    const float4* mp = (const float4*)(MTW + (int)(ev[j] & 0xffffu) * HID + ks8);
#pragma unroll
                    for (int q = 0; q < 4; ++q) {
                        float4 x = mp[q];
                        hacc[4 * q + 0] += x.x; hacc[4 * q + 1] += x.y;
                        hacc[4 * q + 2] += x.z; hacc[4 * q + 3] += x.w;
                    }
                }
                if (2 * j + 1 < deg) {
                    const float4* mp = (const float4*)(MTW + (int)(ev[j] >> 16) * HID + ks8);
#pragma unroll
                    for (int q = 0; q < 4; ++q) {
                        float4 x = mp[q];
                        hacc[4 * q + 0] += x.x; hacc[4 * q + 1] += x.y;
                        hacc[4 * q + 2] += x.z; hacc[4 * q + 3] += x.w;
                    }
                }
            }
        }
        // relu + pack bf16; swizzled chunk store (2x b128, conflict-free)
        unsigned short* rowbase = sH + al * 128;
#pragma unroll
        for (int j = 0; j < 2; ++j) {
            int pc = ((ks8 >> 3) + j) ^ (al & 7);
            uint4 u;
            u.x = bfpack(fmaxf(hacc[8 * j + 0], 0.f), fmaxf(hacc[8 * j + 1], 0.f));
            u.y = bfpack(fmaxf(hacc[8 * j + 2], 0.f), fmaxf(hacc[8 * j + 3], 0.f));
            u.z = bfpack(fmaxf(hacc[8 * j + 4], 0.f), fmaxf(hacc[8 * j + 5], 0.f));
            u.w = bfpack(fmaxf(hacc[8 * j + 6], 0.f), fmaxf(hacc[8 * j + 7], 0.f));
            *(uint4*)(rowbase + pc * 8) = u;
        }
    }
    __syncthreads();

    // segmented block-sum: thread (c, quarter q) walks rows r0..r0+15 in regs
    {
        const int c = tid & 127;
        const int q = tid >> 7;            // 0..3
        const int r0 = q * 16;
        float vals[16];
        int bids[16];
#pragma unroll
        for (int k = 0; k < 16; ++k) {
            int r = r0 + k;
            vals[k] = bff(sH[r * 128 + ((((c >> 3) ^ (r & 7)) << 3) | (c & 7))]);
            bids[k] = sBid[r];
        }
        int prev = (q == 0) ? -2 : sBid[r0 - 1];
        int nxt  = (q == 3) ? -2 : sBid[r0 + 16];
        float run = 0.f;
        int curb = bids[0];
        bool unsafe = (q == 0) || (prev == curb);
#pragma unroll
        for (int k = 0; k < 16; ++k) {
            int b = bids[k];
            if (b != curb) {
                if (curb >= 0) {
                    float* o = out + (size_t)curb * HID + c;
                    if (unsafe) atomicAdd(o, run); else *o = run;
                }
                run = 0.f; curb = b; unsafe = false;
            }
            run += vals[k];
        }
        if (curb >= 0) {
            bool endUnsafe = (q == 3) || (nxt == curb);
            float* o = out + (size_t)curb * HID + c;
            if (unsafe || endUnsafe) atomicAdd(o, run); else *o = run;
        }
    }
}

// ---- K4: out = (S@W2 + cnt*b2)/sqrt(cnt); direct accumulator stores ----
__global__ __launch_bounds__(256, 8) void k_gemm2(
    const unsigned short* __restrict__ wt2, const float* __restrict__ b2,
    const int* __restrict__ cnt, const int* __restrict__ gmask,
    float* __restrict__ out)
{
    __shared__ char lds[16384];          // bf16 swizzled S-tile only
    __shared__ float sCnt[64];
    __shared__ float sScale[64];
    const int base = blockIdx.x * 64;
    const int tid = threadIdx.x;

    if (tid < 64) {
        int rb = base + tid;
        float cf = 0.f, sc = 0.f;
        if (rb < NB) {
            int c = cnt[rb];
            cf = (float)c;
            sc = (gmask[rb] == 0) ? rsqrtf((float)(c < 1 ? 1 : c)) : 0.f;
        }
        sCnt[tid] = cf;
        sScale[tid] = sc;
    }

    // load S tile -> bf16 swizzled LDS; rows k_h1 never wrote
    // (masked or cnt==0) are zeros, NOT loaded
    {
        const int al = tid >> 2;
        const int ks4 = tid & 3;
        const int rb = base + al;
        float v[32];
        if (rb < NB && gmask[rb] == 0 && cnt[rb] > 0) {
            const float4* sp = (const float4*)(out + (size_t)rb * HID + ks4 * 32);
#pragma unroll
            for (int j = 0; j < 8; ++j) {
                float4 x = sp[j];
                v[4 * j + 0] = x.x; v[4 * j + 1] = x.y;
                v[4 * j + 2] = x.z; v[4 * j + 3] = x.w;
            }
        } else {
#pragma unroll
            for (int j = 0; j < 32; ++j) v[j] = 0.f;
        }
        char* rowp = lds + al * 256;
#pragma unroll
        for (int c = 0; c < 4; ++c) {
            uint4 u;
            u.x = bfpack(v[8 * c + 0], v[8 * c + 1]);
            u.y = bfpack(v[8 * c + 2], v[8 * c + 3]);
            u.z = bfpack(v[8 * c + 4], v[8 * c + 5]);
            u.w = bfpack(v[8 * c + 6], v[8 * c + 7]);
            int chunk = (ks4 * 4 + c) ^ (al & 7);
            *(uint4*)(rowp + chunk * 16) = u;
        }
    }
    __syncthreads();

    const int w = tid >> 6;
    const int lane = tid & 63;
    const int rA = w * 16 + (lane & 15);
    const int g4 = lane >> 4;
    const int colb = lane & 15;

    f32x4 acc[8];
    {
        bf16x8 af[4];
#pragma unroll
        for (int k4 = 0; k4 < 4; ++k4) {
            int chunk = (k4 * 4 + g4) ^ (rA & 7);
            af[k4] = *(const bf16x8*)(lds + rA * 256 + chunk * 16);
        }
#pragma unroll
        for (int ct = 0; ct < 8; ++ct) {
            f32x4 a = {0.f, 0.f, 0.f, 0.f};
            const unsigned short* wp = wt2 + (ct * 16 + colb) * HID + g4 * 8;
#pragma unroll
            for (int k4 = 0; k4 < 4; ++k4) {
                bf16x8 bfr = *(const bf16x8*)(wp + k4 * 32);
                a = __builtin_amdgcn_mfma_f32_16x16x32_bf16(af[k4], bfr, a, 0, 0, 0);
            }
            acc[ct] = a;
        }
    }

    // direct stores from accumulators: per (ct,r) each 16-lane group writes
    // 16 consecutive dwords (64B). Masked / cnt==0 rows store exact zeros.
#pragma unroll
    for (int ct = 0; ct < 8; ++ct) {
        int col = ct * 16 + colb;
        float bv = b2[col];
#pragma unroll
        for (int r = 0; r < 4; ++r) {
            int row = w * 16 + g4 * 4 + r;
            int rb = base + row;
            if (rb < NB)
                out[(size_t)rb * HID + col] =
                    (acc[ct][r] + sCnt[row] * bv) * sScale[row];
        }
    }
}

extern "C" void kernel_launch(void* const* d_in, const int* in_sizes, int n_in,
                              void* d_out, int out_size, void* d_ws, size_t ws_size,
                              hipStream_t stream) {
    const int* A          = (const int*)d_in[0];
    const int* bonds      = (const int*)d_in[1];
    const int* block_ids  = (const int*)d_in[2];
    const int* gmask      = (const int*)d_in[3];
    const float* atom_table = (const float*)d_in[4];
    const float* bond_table = (const float*)d_in[5];
    const float* eps      = (const float*)d_in[6];
    const float* W1       = (const float*)d_in[7];
    const float* b1       = (const float*)d_in[8];
    const float* W2       = (const float*)d_in[9];
    const float* b2       = (const float*)d_in[10];
    float* out = (float*)d_out;
    char* ws = (char*)d_ws;

    // ws layout (bytes); total ~12.62 MB (identical to proven r8-r13 layout)
    int* cnt    = (int*)(ws + 0);             // [NB]        0 .. 400000
    int* adeg   = (int*)(ws + 400000);        // [NAC]       .. 1488000
    int* totB   = (int*)(ws + 1488000);       // [NCHUNK]    .. 1489956
    int* nctx   = (int*)(ws + 1490000);       // [1]
    float* TAW  = (float*)(ws + 1490048);     // [128*128]   .. 1555584
    float* MTW  = (float*)(ws + 1555584);     // [640*128]   .. 1883264
    unsigned short* wt2 = (unsigned short*)(ws + 1883264);   // [128*128] .. 1916032
    int* acp    = (int*)(ws + 1916032);       // [NA]        .. 3916032
    int* catomA = (int*)(ws + 3916032);       // [NAC]       .. 5004032
    unsigned short* buf2 = (unsigned short*)(ws + 5004032);  // [NAC*CAPA] .. 12620032

    // no hipMemsetAsync: cnt+adeg zeroed by k_scanprep's zero branch

    k_scanprep<<<NCHUNK + 128 + NZB, 256, 0, stream>>>(
        block_ids, gmask, A, cnt, acp, totB,
        atom_table, bond_table, W1, W2, b1, eps, TAW, MTW, wt2);
    k_escfat<<<NEB + NAB, 256, 0, stream>>>(
        bonds, acp, totB, block_ids, adeg, buf2, catomA, nctx, cnt, out);
    k_h1<<<NT, 512, 0, stream>>>(catomA, nctx, adeg, buf2, TAW, MTW, out);
    k_gemm2<<<NBT, 256, 0, stream>>>(wt2, b2, cnt, gmask, out);
}

// Round 15
// 125.340 us; speedup vs baseline: 1.0537x; 1.0537x over previous
//
#include <hip/hip_runtime.h>
#include <math.h>

#define NA 500000
#define NE 1000000
#define NB 100000
#define HID 128
#define NCHUNK 489      // ceil(NA / 1024)
#define NT 7813         // ceil(NA / 64) worst-case ctx tiles
#define NBT 1563        // ceil(NB / 64)
#define NAC 272000      // capacity for compacted ctx atoms (~250K actual)
#define CAPA 14         // per-atom kept-degree cap; Poisson(1), P(>=14 anywhere) ~ 1e-6
#define NEB 977         // edge-quad blocks in k_escfat
#define NAB 1954        // atom blocks in k_escfat

typedef __attribute__((ext_vector_type(8))) short bf16x8;
typedef __attribute__((ext_vector_type(4))) float f32x4;

// fp32 -> bf16 round-to-nearest-even
static __device__ __forceinline__ unsigned short bf1(float a) {
    unsigned ua = __float_as_uint(a);
    ua += 0x7fffu + ((ua >> 16) & 1u);
    return (unsigned short)(ua >> 16);
}
static __device__ __forceinline__ unsigned bfpack(float a, float b) {
    unsigned ua = __float_as_uint(a); ua += 0x7fffu + ((ua >> 16) & 1u);
    unsigned ub = __float_as_uint(b); ub += 0x7fffu + ((ub >> 16) & 1u);
    return (ua >> 16) | (ub & 0xffff0000u);
}
static __device__ __forceinline__ float bff(unsigned short h) {
    return __uint_as_float((unsigned)h << 16);
}

// ---- K1 (fat): blocks [0,489): ctx scan + cnt histogram (acp packs A);
//                [489,553): TAW/MTW prep; [553,617): wt2 ----
__global__ __launch_bounds__(256) void k_scanprep(
    const int* __restrict__ block_ids, const int* __restrict__ gmask,
    const int* __restrict__ A,
    int* __restrict__ cnt, int* __restrict__ acp, int* __restrict__ totB,
    const float* __restrict__ at, const float* __restrict__ bt,
    const float* __restrict__ W1, const float* __restrict__ W2,
    const float* __restrict__ b1, const float* __restrict__ epsp,
    float* __restrict__ TAW, float* __restrict__ MTW,
    unsigned short* __restrict__ wt2)
{
    __shared__ float smem[17920];   // 70 KB, shared by all branches
    const int blk = blockIdx.x;
    const int tid = threadIdx.x;

    if (blk < NCHUNK) {
        // per-chunk exclusive ctx scan; acp[i] = (prefix<<7)|A[i] or -1
        int* sd = (int*)smem;
        int base = blk * 1024 + tid * 4;
        int c0 = 0, c1 = 0, c2 = 0, c3 = 0;
        int4 av = make_int4(0, 0, 0, 0);
        if (base < NA) {               // NA%4==0 -> all 4 valid
            int4 b = *(const int4*)(block_ids + base);
            av = *(const int4*)(A + base);
            atomicAdd(&cnt[b.x], 1); atomicAdd(&cnt[b.y], 1);
            atomicAdd(&cnt[b.z], 1); atomicAdd(&cnt[b.w], 1);
            c0 = (gmask[b.x] == 0); c1 = (gmask[b.y] == 0);
            c2 = (gmask[b.z] == 0); c3 = (gmask[b.w] == 0);
        }
        int s = c0 + c1 + c2 + c3;
        sd[tid] = s;
        __syncthreads();
        for (int o = 1; o < 256; o <<= 1) {
            int x = (tid >= o) ? sd[tid - o] : 0;
            __syncthreads();
            sd[tid] += x;
            __syncthreads();
        }
        int run = sd[tid] - s;
        if (tid == 255) totB[blk] = sd[255];
        if (base < NA) {
            acp[base + 0] = c0 ? ((run << 7) | av.x) : -1; run += c0;
            acp[base + 1] = c1 ? ((run << 7) | av.y) : -1; run += c1;
            acp[base + 2] = c2 ? ((run << 7) | av.z) : -1; run += c2;
            acp[base + 3] = c3 ? ((run << 7) | av.w) : -1;
        }
    } else if (blk < NCHUNK + 64) {
        // TAW' = (1+eps)*(at@W1)+b1 (rows 0..127); MTW = relu(at+bt)@W1 (rows 128..767)
        const int blk2 = blk - NCHUNK;
        float* sW1 = smem;                              // 64 KB
        float (*sIn)[HID] = (float(*)[HID])(smem + 16384);  // 6 KB
        for (int i = tid; i < HID * HID / 4; i += 256)
            ((float4*)sW1)[i] = ((const float4*)W1)[i];
        for (int x = tid; x < 12 * HID; x += 256) {
            int rr = x >> 7, k = x & 127;
            int r = blk2 * 12 + rr;                     // 0..767
            float v = 0.f;
            if (r < 128) v = at[r * HID + k];
            else {
                int m = r - 128;
                int a = m / 5, bb = m - a * 5;
                v = fmaxf(at[a * HID + k] + bt[bb * HID + k], 0.f);
            }
            sIn[rr][k] = v;
        }
        __syncthreads();
        float ope = 1.0f + epsp[0];
        for (int x = tid; x < 12 * HID; x += 256) {
            int rr = x >> 7, c = x & 127;
            int r = blk2 * 12 + rr;
            float acc = 0.f;
#pragma unroll 8
            for (int k = 0; k < HID; ++k)
                acc = fmaf(sIn[rr][k], sW1[k * HID + c], acc);
            if (r < 128) TAW[r * HID + c] = ope * acc + b1[c];
            else         MTW[(r - 128) * HID + c] = acc;
        }
    } else {
        // wt2 = bf16 col-major W2 [n][k]
        int id = (blk - NCHUNK - 64) * 256 + tid;       // 0..16383
        int n = id >> 7, k = id & 127;
        wt2[id] = bf1(W2[k * HID + n]);
    }
}

// ---- K2 (fat): every block scans totB (2KB) in-LDS; then
//      blocks [0,NEB): edge scatter with global pd;
//      blocks [NEB,NEB+NAB): catomA build + nctx + TILE-boundary row zeroing ----
__global__ __launch_bounds__(256) void k_escfat(
    const int* __restrict__ bonds, const int* __restrict__ acp,
    const int* __restrict__ totB, const int* __restrict__ block_ids,
    int* __restrict__ adeg, unsigned short* __restrict__ buf2,
    int* __restrict__ catomA, int* __restrict__ nctxp,
    float* __restrict__ out)
{
    __shared__ int sT[512];
    __shared__ int sS[256];
    const int t = threadIdx.x;
    // exclusive scan of chunk totals (pairs per thread)
    int a0 = (2 * t     < NCHUNK) ? totB[2 * t]     : 0;
    int a1 = (2 * t + 1 < NCHUNK) ? totB[2 * t + 1] : 0;
    int s = a0 + a1;
    sS[t] = s;
    __syncthreads();
    for (int o = 1; o < 256; o <<= 1) {
        int x = (t >= o) ? sS[t - o] : 0;
        __syncthreads();
        sS[t] += x;
        __syncthreads();
    }
    int run = sS[t] - s;
    sT[2 * t] = run;
    sT[2 * t + 1] = run + a0;
    if (blockIdx.x == 0 && t == 255) nctxp[0] = sS[255];
    __syncthreads();

    if (blockIdx.x < NEB) {
        int e4 = blockIdx.x * 256 + t;           // edge-quad id
        if (e4 >= NE / 4) return;
        const int4* b4 = (const int4*)bonds;
        int4 q0 = b4[e4 * 3 + 0];
        int4 q1 = b4[e4 * 3 + 1];
        int4 q2 = b4[e4 * 3 + 2];
        int ss[4] = {q0.x, q0.w, q1.z, q2.y};
        int dd[4] = {q0.y, q1.x, q1.w, q2.z};
        int tt[4] = {q0.z, q1.y, q2.x, q2.w};
#pragma unroll
        for (int k = 0; k < 4; ++k) {
            int va = acp[ss[k]];
            int vd = acp[dd[k]];
            if ((va | vd) >= 0) {                // both ctx
                int pd = (vd >> 7) + sT[dd[k] >> 10];
                int slot = atomicAdd(&adeg[pd], 1);
                if (slot < CAPA)
                    buf2[(size_t)pd * CAPA + slot] =
                        (unsigned short)((va & 127) * 5 + tt[k]);   // < 640
            }
        }
    } else {
        int i = (blockIdx.x - NEB) * 256 + t;
        if (i < NA) {
            int v = acp[i];
            if (v >= 0) {
                int p = (v >> 7) + sT[i >> 10];
                int bid = block_ids[i];
                catomA[p] = (bid << 7) | (v & 127);   // bid<2^17
                int pm = p & 63;
                if (pm == 0 || pm == 63) {
                    // TILE-boundary position: zero its out row (atomic target)
                    float4 z = make_float4(0.f, 0.f, 0.f, 0.f);
                    float4* o = (float4*)(out + (size_t)bid * HID);
#pragma unroll
                    for (int j = 0; j < 32; ++j) o[j] = z;
                }
            }
        }
    }
}

// ---- K3: 512-thread tiles; 8 threads/atom walk; swizzled bf16 sH;
//          segsum with cross-quarter LDS merge (atomics only at tile edges) ----
__global__ __launch_bounds__(512, 8) void k_h1(
    const int* __restrict__ catomA, const int* __restrict__ nctxp,
    const int* __restrict__ adeg, const unsigned short* __restrict__ buf2,
    const float* __restrict__ TAW, const float* __restrict__ MTW,
    float* __restrict__ out)
{
    __shared__ unsigned short sH[64 * 128];   // 16 KB, chunk-XOR swizzled
    __shared__ float sP[4][2][128];           // 4 KB: head/tail run partials
    __shared__ int sAid[64];
    __shared__ int sBid[64];
    __shared__ int sDeg[64];

    const int nctx = nctxp[0];
    const int base = blockIdx.x * 64;
    if (base >= nctx) return;          // uniform exit
    const int tid = threadIdx.x;

    if (tid < 64) {
        int idx = base + tid;
        if (idx < nctx) {
            int ca = catomA[idx];
            sAid[tid] = ca & 127;
            sBid[tid] = ca >> 7;
            int d = adeg[idx];
            sDeg[tid] = d < CAPA ? d : CAPA;
        } else {
            sAid[tid] = -1; sBid[tid] = -1; sDeg[tid] = 0;
        }
    }
    __syncthreads();

    // compute: thread (al, ks8) owns 16 cols of atom al
    {
        const int al = tid >> 3;            // atom-local 0..63
        const int ks8 = (tid & 7) * 16;     // col-segment base
        const int aid = sAid[al];
        float hacc[16];
#pragma unroll
        for (int j = 0; j < 16; ++j) hacc[j] = 0.f;
        if (aid >= 0) {
            const int deg = sDeg[al];
            const unsigned* ep32 = (const unsigned*)(buf2 + (size_t)(base + al) * CAPA);
            unsigned ev[7];
#pragma unroll
            for (int j = 0; j < 7; ++j)
                if (2 * j < deg) ev[j] = ep32[j];
            const float4* tp = (const float4*)(TAW + aid * HID + ks8);
#pragma unroll
            for (int j = 0; j < 4; ++j) {
                float4 v = tp[j];
                hacc[4 * j + 0] = v.x; hacc[4 * j + 1] = v.y;
                hacc[4 * j + 2] = v.z; hacc[4 * j + 3] = v.w;
            }
#pragma unroll
            for (int j = 0; j < 7; ++j) {
                if (2 * j < deg) {
                    const float4* mp = (const float4*)(MTW + (int)(ev[j] & 0xffffu) * HID + ks8);
#pragma unroll
                    for (int q = 0; q < 4; ++q) {
                        float4 x = mp[q];
                        hacc[4 * q + 0] += x.x; hacc[4 * q + 1] += x.y;
                        hacc[4 * q + 2] += x.z; hacc[4 * q + 3] += x.w;
                    }
                }
                if (2 * j + 1 < deg) {
                    const float4* mp = (const float4*)(MTW + (int)(ev[j] >> 16) * HID + ks8);
#pragma unroll
                    for (int q = 0; q < 4; ++q) {
                        float4 x = mp[q];
                        hacc[4 * q + 0] += x.x; hacc[4 * q + 1] += x.y;
                        hacc[4 * q + 2] += x.z; hacc[4 * q + 3] += x.w;
                    }
                }
            }
        }
        // relu + pack bf16; swizzled chunk store (2x b128, conflict-free)
        unsigned short* rowbase = sH + al * 128;
#pragma unroll
        for (int j = 0; j < 2; ++j) {
            int pc = ((ks8 >> 3) + j) ^ (al & 7);
            uint4 u;
            u.x = bfpack(fmaxf(hacc[8 * j + 0], 0.f), fmaxf(hacc[8 * j + 1], 0.f));
            u.y = bfpack(fmaxf(hacc[8 * j + 2], 0.f), fmaxf(hacc[8 * j + 3], 0.f));
            u.z = bfpack(fmaxf(hacc[8 * j + 4], 0.f), fmaxf(hacc[8 * j + 5], 0.f));
            u.w = bfpack(fmaxf(hacc[8 * j + 6], 0.f), fmaxf(hacc[8 * j + 7], 0.f));
            *(uint4*)(rowbase + pc * 8) = u;
        }
    }
    __syncthreads();

    // phase 1: per-quarter walk; interior runs plain-store (sole writer);
    // head/tail run partials -> sP. bids are non-decreasing (sorted), with a
    // possible -1 padding suffix in the last tile.
    {
        const int c = tid & 127;
        const int q = tid >> 7;            // 0..3
        const int r0 = q * 16;
        float vals[16];
        int bids[16];
#pragma unroll
        for (int k = 0; k < 16; ++k) {
            int r = r0 + k;
            vals[k] = bff(sH[r * 128 + ((((c >> 3) ^ (r & 7)) << 3) | (c & 7))]);
            bids[k] = sBid[r];
        }
        float run = vals[0];
        int curb = bids[0];
        bool isHead = true;
#pragma unroll
        for (int k = 1; k < 16; ++k) {
            int b = bids[k];
            if (b != curb) {
                if (isHead) { sP[q][0][c] = run; isHead = false; }
                else if (curb >= 0) out[(size_t)curb * HID + c] = run;
                run = 0.f; curb = b;
            }
            run += vals[k];
        }
        if (isHead) sP[q][0][c] = run;     // single-run quarter (bids[0]==bids[15])
        else        sP[q][1][c] = run;     // tail partial
    }
    __syncthreads();

    // phase 2: chain-merge quarters per column; atomics only for runs touching
    // row 0 (us) or row 63 (final emit) — those rows pre-zeroed by k_escfat
    if (tid < 128) {
        const int c = tid;
        int curb = sBid[0];
        float cur = sP[0][0][c];
        bool us = true;
#pragma unroll
        for (int q = 0; q < 4; ++q) {
            if (q > 0) {
                int hb = sBid[q * 16];
                if (hb == curb) cur += sP[q][0][c];
                else {
                    if (curb >= 0) {
                        float* o = out + (size_t)curb * HID + c;
                        if (us) atomicAdd(o, cur); else *o = cur;
                    }
                    curb = hb; cur = sP[q][0][c]; us = false;
                }
            }
            if (sBid[q * 16] != sBid[q * 16 + 15]) {   // multi-run quarter
                if (curb >= 0) {
                    float* o = out + (size_t)curb * HID + c;
                    if (us) atomicAdd(o, cur); else *o = cur;
                }
                curb = sBid[q * 16 + 15]; cur = sP[q][1][c]; us = false;
            }
        }
        if (curb >= 0)
            atomicAdd(out + (size_t)curb * HID + c, cur);   // touches row 63
    }
}

// ---- K4: out = (S@W2 + cnt*b2)/sqrt(cnt); direct accumulator stores ----
__global__ __launch_bounds__(256, 8) void k_gemm2(
    const unsigned short* __restrict__ wt2, const float* __restrict__ b2,
    const int* __restrict__ cnt, const int* __restrict__ gmask,
    float* __restrict__ out)
{
    __shared__ char lds[16384];          // bf16 swizzled S-tile only
    __shared__ float sCnt[64];
    __shared__ float sScale[64];
    const int base = blockIdx.x * 64;
    const int tid = threadIdx.x;

    if (tid < 64) {
        int rb = base + tid;
        float cf = 0.f, sc = 0.f;
        if (rb < NB) {
            int c = cnt[rb];
            cf = (float)c;
            sc = (gmask[rb] == 0) ? rsqrtf((float)(c < 1 ? 1 : c)) : 0.f;
        }
        sCnt[tid] = cf;
        sScale[tid] = sc;
    }

    // load S tile -> bf16 swizzled LDS; rows k_h1 never wrote
    // (masked or cnt==0) are zeros, NOT loaded
    {
        const int al = tid >> 2;
        const int ks4 = tid & 3;
        const int rb = base + al;
        float v[32];
        if (rb < NB && gmask[rb] == 0 && cnt[rb] > 0) {
            const float4* sp = (const float4*)(out + (size_t)rb * HID + ks4 * 32);
#pragma unroll
            for (int j = 0; j < 8; ++j) {
                float4 x = sp[j];
                v[4 * j + 0] = x.x; v[4 * j + 1] = x.y;
                v[4 * j + 2] = x.z; v[4 * j + 3] = x.w;
            }
        } else {
#pragma unroll
            for (int j = 0; j < 32; ++j) v[j] = 0.f;
        }
        char* rowp = lds + al * 256;
#pragma unroll
        for (int c = 0; c < 4; ++c) {
            uint4 u;
            u.x = bfpack(v[8 * c + 0], v[8 * c + 1]);
            u.y = bfpack(v[8 * c + 2], v[8 * c + 3]);
            u.z = bfpack(v[8 * c + 4], v[8 * c + 5]);
            u.w = bfpack(v[8 * c + 6], v[8 * c + 7]);
            int chunk = (ks4 * 4 + c) ^ (al & 7);
            *(uint4*)(rowp + chunk * 16) = u;
        }
    }
    __syncthreads();

    const int w = tid >> 6;
    const int lane = tid & 63;
    const int rA = w * 16 + (lane & 15);
    const int g4 = lane >> 4;
    const int colb = lane & 15;

    f32x4 acc[8];
    {
        bf16x8 af[4];
#pragma unroll
        for (int k4 = 0; k4 < 4; ++k4) {
            int chunk = (k4 * 4 + g4) ^ (rA & 7);
            af[k4] = *(const bf16x8*)(lds + rA * 256 + chunk * 16);
        }
#pragma unroll
        for (int ct = 0; ct < 8; ++ct) {
            f32x4 a = {0.f, 0.f, 0.f, 0.f};
            const unsigned short* wp = wt2 + (ct * 16 + colb) * HID + g4 * 8;
#pragma unroll
            for (int k4 = 0; k4 < 4; ++k4) {
                bf16x8 bfr = *(const bf16x8*)(wp + k4 * 32);
                a = __builtin_amdgcn_mfma_f32_16x16x32_bf16(af[k4], bfr, a, 0, 0, 0);
            }
            acc[ct] = a;
        }
    }

    // direct stores from accumulators: per (ct,r) each 16-lane group writes
    // 16 consecutive dwords (64B). Masked / cnt==0 rows store exact zeros.
#pragma unroll
    for (int ct = 0; ct < 8; ++ct) {
        int col = ct * 16 + colb;
        float bv = b2[col];
#pragma unroll
        for (int r = 0; r < 4; ++r) {
            int row = w * 16 + g4 * 4 + r;
            int rb = base + row;
            if (rb < NB)
                out[(size_t)rb * HID + col] =
                    (acc[ct][r] + sCnt[row] * bv) * sScale[row];
        }
    }
}

extern "C" void kernel_launch(void* const* d_in, const int* in_sizes, int n_in,
                              void* d_out, int out_size, void* d_ws, size_t ws_size,
                              hipStream_t stream) {
    const int* A          = (const int*)d_in[0];
    const int* bonds      = (const int*)d_in[1];
    const int* block_ids  = (const int*)d_in[2];
    const int* gmask      = (const int*)d_in[3];
    const float* atom_table = (const float*)d_in[4];
    const float* bond_table = (const float*)d_in[5];
    const float* eps      = (const float*)d_in[6];
    const float* W1       = (const float*)d_in[7];
    const float* b1       = (const float*)d_in[8];
    const float* W2       = (const float*)d_in[9];
    const float* b2       = (const float*)d_in[10];
    float* out = (float*)d_out;
    char* ws = (char*)d_ws;

    // ws layout (bytes); total ~12.62 MB (identical to proven r8-r14 layout)
    int* cnt    = (int*)(ws + 0);             // [NB]        0 .. 400000
    int* adeg   = (int*)(ws + 400000);        // [NAC]       .. 1488000
    int* totB   = (int*)(ws + 1488000);       // [NCHUNK]    .. 1489956
    int* nctx   = (int*)(ws + 1490000);       // [1]
    float* TAW  = (float*)(ws + 1490048);     // [128*128]   .. 1555584
    float* MTW  = (float*)(ws + 1555584);     // [640*128]   .. 1883264
    unsigned short* wt2 = (unsigned short*)(ws + 1883264);   // [128*128] .. 1916032
    int* acp    = (int*)(ws + 1916032);       // [NA]        .. 3916032
    int* catomA = (int*)(ws + 3916032);       // [NAC]       .. 5004032
    unsigned short* buf2 = (unsigned short*)(ws + 5004032);  // [NAC*CAPA] .. 12620032

    hipMemsetAsync(cnt, 0, 1488000, stream);                 // cnt + adeg (cheap)

    k_scanprep<<<NCHUNK + 128, 256, 0, stream>>>(
        block_ids, gmask, A, cnt, acp, totB,
        atom_table, bond_table, W1, W2, b1, eps, TAW, MTW, wt2);
    k_escfat<<<NEB + NAB, 256, 0, stream>>>(
        bonds, acp, totB, block_ids, adeg, buf2, catomA, nctx, out);
    k_h1<<<NT, 512, 0, stream>>>(catomA, nctx, adeg, buf2, TAW, MTW, out);
    k_gemm2<<<NBT, 256, 0, stream>>>(wt2, b2, cnt, gmask, out);
}

// Round 17
// 124.831 us; speedup vs baseline: 1.0580x; 1.0041x over previous
//
#include <hip/hip_runtime.h>
#include <math.h>

#define NA 500000
#define NE 1000000
#define NB 100000
#define HID 128
#define NCHUNK 489      // ceil(NA / 1024)
#define NT 7813         // ceil(NA / 64) worst-case ctx tiles
#define NBT 1563        // ceil(NB / 64)
#define NAC 272000      // capacity for compacted ctx atoms (~250K actual)
#define CAPA 14         // per-atom kept-degree cap; Poisson(1), P(>=14 anywhere) ~ 1e-6
#define NEB 977         // edge-quad blocks in k_escfat
#define NAB 1954        // atom blocks in k_escfat

typedef __attribute__((ext_vector_type(8))) short bf16x8;
typedef __attribute__((ext_vector_type(4))) float f32x4;

// fp32 -> bf16 round-to-nearest-even
static __device__ __forceinline__ unsigned short bf1(float a) {
    unsigned ua = __float_as_uint(a);
    ua += 0x7fffu + ((ua >> 16) & 1u);
    return (unsigned short)(ua >> 16);
}
static __device__ __forceinline__ unsigned bfpack(float a, float b) {
    unsigned ua = __float_as_uint(a); ua += 0x7fffu + ((ua >> 16) & 1u);
    unsigned ub = __float_as_uint(b); ub += 0x7fffu + ((ub >> 16) & 1u);
    return (ua >> 16) | (ub & 0xffff0000u);
}
static __device__ __forceinline__ float bff(unsigned short h) {
    return __uint_as_float((unsigned)h << 16);
}

// ---- K1 (fat): blocks [0,489): ctx scan + cnt histogram (acp packs A);
//                [489,553): TAW/MTW prep; [553,617): wt2 ----
__global__ __launch_bounds__(256) void k_scanprep(
    const int* __restrict__ block_ids, const int* __restrict__ gmask,
    const int* __restrict__ A,
    int* __restrict__ cnt, int* __restrict__ acp, int* __restrict__ totB,
    const float* __restrict__ at, const float* __restrict__ bt,
    const float* __restrict__ W1, const float* __restrict__ W2,
    const float* __restrict__ b1, const float* __restrict__ epsp,
    float* __restrict__ TAW, float* __restrict__ MTW,
    unsigned short* __restrict__ wt2)
{
    __shared__ float smem[17920];   // 70 KB, shared by all branches
    const int blk = blockIdx.x;
    const int tid = threadIdx.x;

    if (blk < NCHUNK) {
        // per-chunk exclusive ctx scan; acp[i] = (prefix<<7)|A[i] or -1
        int* sd = (int*)smem;
        int base = blk * 1024 + tid * 4;
        int c0 = 0, c1 = 0, c2 = 0, c3 = 0;
        int4 av = make_int4(0, 0, 0, 0);
        if (base < NA) {               // NA%4==0 -> all 4 valid
            int4 b = *(const int4*)(block_ids + base);
            av = *(const int4*)(A + base);
            atomicAdd(&cnt[b.x], 1); atomicAdd(&cnt[b.y], 1);
            atomicAdd(&cnt[b.z], 1); atomicAdd(&cnt[b.w], 1);
            c0 = (gmask[b.x] == 0); c1 = (gmask[b.y] == 0);
            c2 = (gmask[b.z] == 0); c3 = (gmask[b.w] == 0);
        }
        int s = c0 + c1 + c2 + c3;
        sd[tid] = s;
        __syncthreads();
        for (int o = 1; o < 256; o <<= 1) {
            int x = (tid >= o) ? sd[tid - o] : 0;
            __syncthreads();
            sd[tid] += x;
            __syncthreads();
        }
        int run = sd[tid] - s;
        if (tid == 255) totB[blk] = sd[255];
        if (base < NA) {
            acp[base + 0] = c0 ? ((run << 7) | av.x) : -1; run += c0;
            acp[base + 1] = c1 ? ((run << 7) | av.y) : -1; run += c1;
            acp[base + 2] = c2 ? ((run << 7) | av.z) : -1; run += c2;
            acp[base + 3] = c3 ? ((run << 7) | av.w) : -1;
        }
    } else if (blk < NCHUNK + 64) {
        // TAW' = (1+eps)*(at@W1)+b1 (rows 0..127); MTW = relu(at+bt)@W1 (rows 128..767)
        const int blk2 = blk - NCHUNK;
        float* sW1 = smem;                              // 64 KB
        float (*sIn)[HID] = (float(*)[HID])(smem + 16384);  // 6 KB
        for (int i = tid; i < HID * HID / 4; i += 256)
            ((float4*)sW1)[i] = ((const float4*)W1)[i];
        for (int x = tid; x < 12 * HID; x += 256) {
            int rr = x >> 7, k = x & 127;
            int r = blk2 * 12 + rr;                     // 0..767
            float v = 0.f;
            if (r < 128) v = at[r * HID + k];
            else {
                int m = r - 128;
                int a = m / 5, bb = m - a * 5;
                v = fmaxf(at[a * HID + k] + bt[bb * HID + k], 0.f);
            }
            sIn[rr][k] = v;
        }
        __syncthreads();
        float ope = 1.0f + epsp[0];
        for (int x = tid; x < 12 * HID; x += 256) {
            int rr = x >> 7, c = x & 127;
            int r = blk2 * 12 + rr;
            float acc = 0.f;
#pragma unroll 8
            for (int k = 0; k < HID; ++k)
                acc = fmaf(sIn[rr][k], sW1[k * HID + c], acc);
            if (r < 128) TAW[r * HID + c] = ope * acc + b1[c];
            else         MTW[(r - 128) * HID + c] = acc;
        }
    } else {
        // wt2 = bf16 col-major W2 [n][k]
        int id = (blk - NCHUNK - 64) * 256 + tid;       // 0..16383
        int n = id >> 7, k = id & 127;
        wt2[id] = bf1(W2[k * HID + n]);
    }
}

// ---- K2 (fat): every block scans totB (2KB) in-LDS; then
//      blocks [0,NEB): edge scatter with global pd;
//      blocks [NEB,NEB+NAB): catomA + nctx + tile-boundary row zero + flag ----
__global__ __launch_bounds__(256) void k_escfat(
    const int* __restrict__ bonds, const int* __restrict__ acp,
    const int* __restrict__ totB, const int* __restrict__ block_ids,
    int* __restrict__ adeg, unsigned short* __restrict__ buf2,
    int* __restrict__ catomA, int* __restrict__ nctxp,
    unsigned* __restrict__ flags, float* __restrict__ out)
{
    __shared__ int sT[512];
    __shared__ int sS[256];
    const int t = threadIdx.x;
    // exclusive scan of chunk totals (pairs per thread)
    int a0 = (2 * t     < NCHUNK) ? totB[2 * t]     : 0;
    int a1 = (2 * t + 1 < NCHUNK) ? totB[2 * t + 1] : 0;
    int s = a0 + a1;
    sS[t] = s;
    __syncthreads();
    for (int o = 1; o < 256; o <<= 1) {
        int x = (t >= o) ? sS[t - o] : 0;
        __syncthreads();
        sS[t] += x;
        __syncthreads();
    }
    int run = sS[t] - s;
    sT[2 * t] = run;
    sT[2 * t + 1] = run + a0;
    if (blockIdx.x == 0 && t == 255) nctxp[0] = sS[255];
    __syncthreads();

    if (blockIdx.x < NEB) {
        int e4 = blockIdx.x * 256 + t;           // edge-quad id
        if (e4 >= NE / 4) return;
        const int4* b4 = (const int4*)bonds;
        int4 q0 = b4[e4 * 3 + 0];
        int4 q1 = b4[e4 * 3 + 1];
        int4 q2 = b4[e4 * 3 + 2];
        int ss[4] = {q0.x, q0.w, q1.z, q2.y};
        int dd[4] = {q0.y, q1.x, q1.w, q2.z};
        int tt[4] = {q0.z, q1.y, q2.x, q2.w};
#pragma unroll
        for (int k = 0; k < 4; ++k) {
            int va = acp[ss[k]];
            int vd = acp[dd[k]];
            if ((va | vd) >= 0) {                // both ctx
                int pd = (vd >> 7) + sT[dd[k] >> 10];
                int slot = atomicAdd(&adeg[pd], 1);
                if (slot < CAPA)
                    buf2[(size_t)pd * CAPA + slot] =
                        (unsigned short)((va & 127) * 5 + tt[k]);   // < 640
            }
        }
    } else {
        int i = (blockIdx.x - NEB) * 256 + t;
        if (i < NA) {
            int v = acp[i];
            if (v >= 0) {
                int p = (v >> 7) + sT[i >> 10];
                int bid = block_ids[i];
                catomA[p] = (bid << 7) | (v & 127);   // bid<2^17
                int pm = p & 63;
                if (pm == 0 || pm == 63) {
                    // tile-boundary position: zero row (f32 atomic target) + flag
                    atomicOr(&flags[bid >> 5], 1u << (bid & 31));
                    float4 z = make_float4(0.f, 0.f, 0.f, 0.f);
                    float4* o = (float4*)(out + (size_t)bid * HID);
#pragma unroll
                    for (int j = 0; j < 32; ++j) o[j] = z;
                }
            }
        }
    }
}

// ---- K3: 512-thread tiles; 8 threads/atom walk; swizzled bf16 sH;
//          segsum: interior rows -> bf16 plain stores (first 256B of the
//          row's own 512B slot); boundary rows -> f32 atomics ----
__global__ __launch_bounds__(512, 8) void k_h1(
    const int* __restrict__ catomA, const int* __restrict__ nctxp,
    const int* __restrict__ adeg, const unsigned short* __restrict__ buf2,
    const float* __restrict__ TAW, const float* __restrict__ MTW,
    float* __restrict__ out)
{
    __shared__ unsigned short sH[64 * 128];   // 16 KB, chunk-XOR swizzled
    __shared__ float sP[4][2][128];           // 4 KB: head/tail run partials
    __shared__ int sAid[64];
    __shared__ int sBid[64];
    __shared__ int sDeg[64];

    const int nctx = nctxp[0];
    const int base = blockIdx.x * 64;
    if (base >= nctx) return;          // uniform exit
    const int tid = threadIdx.x;

    if (tid < 64) {
        int idx = base + tid;
        if (idx < nctx) {
            int ca = catomA[idx];
            sAid[tid] = ca & 127;
            sBid[tid] = ca >> 7;
            int d = adeg[idx];
            sDeg[tid] = d < CAPA ? d : CAPA;
        } else {
            sAid[tid] = -1; sBid[tid] = -1; sDeg[tid] = 0;
        }
    }
    __syncthreads();

    // compute: thread (al, ks8) owns 16 cols of atom al
    {
        const int al = tid >> 3;            // atom-local 0..63
        const int ks8 = (tid & 7) * 16;     // col-segment base
        const int aid = sAid[al];
        float hacc[16];
#pragma unroll
        for (int j = 0; j < 16; ++j) hacc[j] = 0.f;
        if (aid >= 0) {
            const int deg = sDeg[al];
            const unsigned* ep32 = (const unsigned*)(buf2 + (size_t)(base + al) * CAPA);
            unsigned ev[7];
#pragma unroll
            for (int j = 0; j < 7; ++j)
                if (2 * j < deg) ev[j] = ep32[j];
            const float4* tp = (const float4*)(TAW + aid * HID + ks8);
#pragma unroll
            for (int j = 0; j < 4; ++j) {
                float4 v = tp[j];
                hacc[4 * j + 0] = v.x; hacc[4 * j + 1] = v.y;
                hacc[4 * j + 2] = v.z; hacc[4 * j + 3] = v.w;
            }
#pragma unroll
            for (int j = 0; j < 7; ++j) {
                if (2 * j < deg) {
                    const float4* mp = (const float4*)(MTW + (int)(ev[j] & 0xffffu) * HID + ks8);
#pragma unroll
                    for (int q = 0; q < 4; ++q) {
                        float4 x = mp[q];
                        hacc[4 * q + 0] += x.x; hacc[4 * q + 1] += x.y;
                        hacc[4 * q + 2] += x.z; hacc[4 * q + 3] += x.w;
                    }
                }
                if (2 * j + 1 < deg) {
                    const float4* mp = (const float4*)(MTW + (int)(ev[j] >> 16) * HID + ks8);
#pragma unroll
                    for (int q = 0; q < 4; ++q) {
                        float4 x = mp[q];
                        hacc[4 * q + 0] += x.x; hacc[4 * q + 1] += x.y;
                        hacc[4 * q + 2] += x.z; hacc[4 * q + 3] += x.w;
                    }
                }
            }
        }
        // relu + pack bf16; swizzled chunk store (2x b128, conflict-free)
        unsigned short* rowbase = sH + al * 128;
#pragma unroll
        for (int j = 0; j < 2; ++j) {
            int pc = ((ks8 >> 3) + j) ^ (al & 7);
            uint4 u;
            u.x = bfpack(fmaxf(hacc[8 * j + 0], 0.f), fmaxf(hacc[8 * j + 1], 0.f));
            u.y = bfpack(fmaxf(hacc[8 * j + 2], 0.f), fmaxf(hacc[8 * j + 3], 0.f));
            u.z = bfpack(fmaxf(hacc[8 * j + 4], 0.f), fmaxf(hacc[8 * j + 5], 0.f));
            u.w = bfpack(fmaxf(hacc[8 * j + 6], 0.f), fmaxf(hacc[8 * j + 7], 0.f));
            *(uint4*)(rowbase + pc * 8) = u;
        }
    }
    __syncthreads();

    // phase 1: per-quarter walk; interior runs -> bf16 plain store (sole
    // writer, completed sum) into the row's own 512B slot; partials -> sP
    {
        const int c = tid & 127;
        const int q = tid >> 7;            // 0..3
        const int r0 = q * 16;
        float vals[16];
        int bids[16];
#pragma unroll
        for (int k = 0; k < 16; ++k) {
            int r = r0 + k;
            vals[k] = bff(sH[r * 128 + ((((c >> 3) ^ (r & 7)) << 3) | (c & 7))]);
            bids[k] = sBid[r];
        }
        float run = vals[0];
        int curb = bids[0];
        bool isHead = true;
#pragma unroll
        for (int k = 1; k < 16; ++k) {
            int b = bids[k];
            if (b != curb) {
                if (isHead) { sP[q][0][c] = run; isHead = false; }
                else if (curb >= 0)
                    ((unsigned short*)(out + (size_t)curb * HID))[c] = bf1(run);
                run = 0.f; curb = b;
            }
            run += vals[k];
        }
        if (isHead) sP[q][0][c] = run;     // single-run quarter (bids[0]==bids[15])
        else        sP[q][1][c] = run;     // tail partial
    }
    __syncthreads();

    // phase 2: chain-merge quarters; runs touching row 0/63 -> f32 atomics
    // (rows pre-zeroed+flagged by k_escfat); others -> bf16 plain store
    if (tid < 128) {
        const int c = tid;
        int curb = sBid[0];
        float cur = sP[0][0][c];
        bool us = true;
#pragma unroll
        for (int q = 0; q < 4; ++q) {
            if (q > 0) {
                int hb = sBid[q * 16];
                if (hb == curb) cur += sP[q][0][c];
                else {
                    if (curb >= 0) {
                        if (us) atomicAdd(out + (size_t)curb * HID + c, cur);
                        else    ((unsigned short*)(out + (size_t)curb * HID))[c] = bf1(cur);
                    }
                    curb = hb; cur = sP[q][0][c]; us = false;
                }
            }
            if (sBid[q * 16] != sBid[q * 16 + 15]) {   // multi-run quarter
                if (curb >= 0) {
                    if (us) atomicAdd(out + (size_t)curb * HID + c, cur);
                    else    ((unsigned short*)(out + (size_t)curb * HID))[c] = bf1(cur);
                }
                curb = sBid[q * 16 + 15]; cur = sP[q][1][c]; us = false;
            }
        }
        if (curb >= 0)
            atomicAdd(out + (size_t)curb * HID + c, cur);   // touches row 63
    }
}

// ---- K4: out = (S@W2 + cnt*b2)/sqrt(cnt); S read per-row in flagged format ----
__global__ __launch_bounds__(256, 8) void k_gemm2(
    const unsigned short* __restrict__ wt2, const float* __restrict__ b2,
    const int* __restrict__ cnt, const int* __restrict__ gmask,
    const unsigned* __restrict__ flags, float* __restrict__ out)
{
    __shared__ char lds[16384];          // bf16 swizzled S-tile only
    __shared__ float sCnt[64];
    __shared__ float sScale[64];
    const int base = blockIdx.x * 64;
    const int tid = threadIdx.x;

    if (tid < 64) {
        int rb = base + tid;
        float cf = 0.f, sc = 0.f;
        if (rb < NB) {
            int c = cnt[rb];
            cf = (float)c;
            sc = (gmask[rb] == 0) ? rsqrtf((float)(c < 1 ? 1 : c)) : 0.f;
        }
        sCnt[tid] = cf;
        sScale[tid] = sc;
    }

    // load S tile -> bf16 swizzled LDS; format per flag bit
    {
        const int al = tid >> 2;
        const int ks4 = tid & 3;
        const int rb = base + al;
        char* rowp = lds + al * 256;
        bool live = (rb < NB) && (gmask[rb] == 0) && (cnt[rb] > 0);
        bool fl = live && (((flags[rb >> 5] >> (rb & 31)) & 1u) != 0);
        if (live && !fl) {
            // bf16 row: first 256B of the row's own 512B slot
            const unsigned short* srow = (const unsigned short*)(out + (size_t)rb * HID);
            const uint4* sp16 = (const uint4*)(srow + ks4 * 32);
#pragma unroll
            for (int c = 0; c < 4; ++c) {
                uint4 u = sp16[c];
                int chunk = (ks4 * 4 + c) ^ (al & 7);
                *(uint4*)(rowp + chunk * 16) = u;
            }
        } else {
            float v[32];
            if (fl) {
                const float4* sp = (const float4*)(out + (size_t)rb * HID + ks4 * 32);
#pragma unroll
                for (int j = 0; j < 8; ++j) {
                    float4 x = sp[j];
                    v[4 * j + 0] = x.x; v[4 * j + 1] = x.y;
                    v[4 * j + 2] = x.z; v[4 * j + 3] = x.w;
                }
            } else {
#pragma unroll
                for (int j = 0; j < 32; ++j) v[j] = 0.f;
            }
#pragma unroll
            for (int c = 0; c < 4; ++c) {
                uint4 u;
                u.x = bfpack(v[8 * c + 0], v[8 * c + 1]);
                u.y = bfpack(v[8 * c + 2], v[8 * c + 3]);
                u.z = bfpack(v[8 * c + 4], v[8 * c + 5]);
                u.w = bfpack(v[8 * c + 6], v[8 * c + 7]);
                int chunk = (ks4 * 4 + c) ^ (al & 7);
                *(uint4*)(rowp + chunk * 16) = u;
            }
        }
    }
    __syncthreads();

    const int w = tid >> 6;
    const int lane = tid & 63;
    const int rA = w * 16 + (lane & 15);
    const int g4 = lane >> 4;
    const int colb = lane & 15;

    f32x4 acc[8];
    {
        bf16x8 af[4];
#pragma unroll
        for (int k4 = 0; k4 < 4; ++k4) {
            int chunk = (k4 * 4 + g4) ^ (rA & 7);
            af[k4] = *(const bf16x8*)(lds + rA * 256 + chunk * 16);
        }
#pragma unroll
        for (int ct = 0; ct < 8; ++ct) {
            f32x4 a = {0.f, 0.f, 0.f, 0.f};
            const unsigned short* wp = wt2 + (ct * 16 + colb) * HID + g4 * 8;
#pragma unroll
            for (int k4 = 0; k4 < 4; ++k4) {
                bf16x8 bfr = *(const bf16x8*)(wp + k4 * 32);
                a = __builtin_amdgcn_mfma_f32_16x16x32_bf16(af[k4], bfr, a, 0, 0, 0);
            }
            acc[ct] = a;
        }
    }

    // direct stores from accumulators: per (ct,r) each 16-lane group writes
    // 16 consecutive dwords (64B). Masked / cnt==0 rows store exact zeros.
#pragma unroll
    for (int ct = 0; ct < 8; ++ct) {
        int col = ct * 16 + colb;
        float bv = b2[col];
#pragma unroll
        for (int r = 0; r < 4; ++r) {
            int row = w * 16 + g4 * 4 + r;
            int rb = base + row;
            if (rb < NB)
                out[(size_t)rb * HID + col] =
                    (acc[ct][r] + sCnt[row] * bv) * sScale[row];
        }
    }
}

extern "C" void kernel_launch(void* const* d_in, const int* in_sizes, int n_in,
                              void* d_out, int out_size, void* d_ws, size_t ws_size,
                              hipStream_t stream) {
    const int* A          = (const int*)d_in[0];
    const int* bonds      = (const int*)d_in[1];
    const int* block_ids  = (const int*)d_in[2];
    const int* gmask      = (const int*)d_in[3];
    const float* atom_table = (const float*)d_in[4];
    const float* bond_table = (const float*)d_in[5];
    const float* eps      = (const float*)d_in[6];
    const float* W1       = (const float*)d_in[7];
    const float* b1       = (const float*)d_in[8];
    const float* W2       = (const float*)d_in[9];
    const float* b2       = (const float*)d_in[10];
    float* out = (float*)d_out;
    char* ws = (char*)d_ws;

    // ws layout (bytes); total ~12.63 MB
    int* cnt    = (int*)(ws + 0);              // [NB]        0 .. 400000
    int* adeg   = (int*)(ws + 400000);         // [NAC]       .. 1488000
    unsigned* flags = (unsigned*)(ws + 1488000); // [3136 u32] .. 1500544 (bitmask)
    int* totB   = (int*)(ws + 1500544);        // [NCHUNK]    .. 1502500
    int* nctx   = (int*)(ws + 1502528);        // [1]
    float* TAW  = (float*)(ws + 1502592);      // [128*128]   .. 1568128
    float* MTW  = (float*)(ws + 1568128);      // [640*128]   .. 1895808
    unsigned short* wt2 = (unsigned short*)(ws + 1895808);   // [128*128] .. 1928576
    int* acp    = (int*)(ws + 1928576);        // [NA]        .. 3928576
    int* catomA = (int*)(ws + 3928576);        // [NAC]       .. 5016576
    unsigned short* buf2 = (unsigned short*)(ws + 5016576);  // [NAC*CAPA] .. 12632576

    hipMemsetAsync(cnt, 0, 1500544, stream);   // cnt + adeg + flags

    k_scanprep<<<NCHUNK + 128, 256, 0, stream>>>(
        block_ids, gmask, A, cnt, acp, totB,
        atom_table, bond_table, W1, W2, b1, eps, TAW, MTW, wt2);
    k_escfat<<<NEB + NAB, 256, 0, stream>>>(
        bonds, acp, totB, block_ids, adeg, buf2, catomA, nctx, flags, out);
    k_h1<<<NT, 512, 0, stream>>>(catomA, nctx, adeg, buf2, TAW, MTW, out);
    k_gemm2<<<NBT, 256, 0, stream>>>(wt2, b2, cnt, gmask, flags, out);
}